// Round 1
// baseline (1872.280 us; speedup 1.0000x reference)
//
#include <hip/hip_runtime.h>
#include <hip/hip_bf16.h>

// Problem constants
#define NND 50000      // nodes
#define NED 800000     // edges (without self-loops)
#define INC 10
#define HID 96
#define OUTC 48
#define NOUT (NND*OUTC)   // 2,400,000 per output tensor

typedef __hip_bfloat16 bf16;

// ---- workspace float layout (after a 16-byte flag header) ----
// converted fp32 copies of inputs:
#define XF_O   0L                 // 500000  (x: N x 10)
#define W1F_O  500000L            // 960
#define B1F_O  500960L            // 96
#define WMF_O  501056L            // 4608
#define BMF_O  505664L            // 48
#define WLF_O  505712L            // 4608
#define BLF_O  510320L            // 48
// working arrays:
#define DIS_O  510368L            // N      (deg, then rsqrt in place)
#define AGGX_O 560368L            // N*10
#define H_O    1060368L           // N*96
#define AGGH_O 5860368L           // N*96
#define WS_FLOATS 10660368L       // ~40.7 MB + 16B header

__device__ __forceinline__ float b2f(bf16 v) { return __bfloat162float(v); }

__device__ __forceinline__ void atomAddF(float* p, float v) {
    unsafeAtomicAdd(p, v);   // native global_atomic_add_f32 on gfx950
}

// edge-index accessors: iw=1 -> int64 storage (low word at 2*e), iw=0 -> int32
__device__ __forceinline__ int rowIdx(const int* ei, int e, int iw) {
    return iw ? ei[2 * e] : ei[e];
}
__device__ __forceinline__ int colIdx(const int* ei, int e, int iw) {
    return iw ? ei[2 * (NED + e)] : ei[NED + e];
}

// K0: runtime dtype sniffer (deterministic, same work every call)
__global__ __launch_bounds__(256) void k_sniff(const int* ei, const unsigned short* xs, int* flags) {
    __shared__ int s_oddnz, s_big;
    if (threadIdx.x == 0) { s_oddnz = 0; s_big = 0; }
    __syncthreads();
    int t = threadIdx.x;
    // int64 detection: if edge_index stored as int64 (values < 2^31), every odd
    // int32 word is 0. With real int32 data P(all zero) ~ (2e-5)^128 = 0.
    if (t < 128) {
        if (ei[2 * t + 1] != 0) atomicOr(&s_oddnz, 1);
    }
    // bf16-vs-fp32 detection: interpret first 2048 uint16 of x as bf16. Genuine
    // bf16 N(0,1) data stays |v|<64; fp32 data's low mantissa halves look like
    // random exponents -> ~half exceed 64 (or NaN).
    for (int k = 0; k < 8; ++k) {
        unsigned short u = xs[t * 8 + k];
        float f = __uint_as_float(((unsigned int)u) << 16);
        if (!(fabsf(f) < 64.0f)) atomicOr(&s_big, 1);
    }
    __syncthreads();
    if (threadIdx.x == 0) {
        flags[0] = (s_oddnz == 0) ? 1 : 0;  // iw: 1 = int64
        flags[1] = s_big ? 1 : 0;           // ff: 1 = fp32
    }
}

// K1: convert all float inputs to fp32 in workspace
#define CVT_TOT 510368
__global__ __launch_bounds__(256) void k_convert(const void* x, const void* w1, const void* b1,
                                                 const void* wm, const void* bm,
                                                 const void* wl, const void* bl,
                                                 const int* flags, float* F) {
    int i = blockIdx.x * 256 + threadIdx.x;
    if (i >= CVT_TOT) return;
    int ff = flags[1];
    const void* src; long off;
    if      (i < 500000) { src = x;  off = i; }
    else if (i < 500960) { src = w1; off = i - 500000; }
    else if (i < 501056) { src = b1; off = i - 500960; }
    else if (i < 505664) { src = wm; off = i - 501056; }
    else if (i < 505712) { src = bm; off = i - 505664; }
    else if (i < 510320) { src = wl; off = i - 505712; }
    else                 { src = bl; off = i - 510320; }
    float v = ff ? ((const float*)src)[off] : b2f(((const bf16*)src)[off]);
    F[i] = v;
}

// K2: degree over col (self-loop +1 folded into K3)
__global__ __launch_bounds__(256) void k_deg(const int* ei, const int* flags, float* F) {
    int e = blockIdx.x * 256 + threadIdx.x;
    if (e >= NED) return;
    int iw = flags[0];
    atomAddF(F + DIS_O + colIdx(ei, e, iw), 1.0f);
}

// K3: dis = rsqrt(deg+1)
__global__ __launch_bounds__(256) void k_dis(float* F) {
    int i = blockIdx.x * 256 + threadIdx.x;
    if (i >= NND) return;
    F[DIS_O + i] = rsqrtf(F[DIS_O + i] + 1.0f);
}

// K4: agg_x[c] += norm * x[r]   (10 features per edge)
__global__ __launch_bounds__(256) void k_aggx(const int* ei, const int* flags, float* F) {
    int e = blockIdx.x * 256 + threadIdx.x;
    if (e >= NED) return;
    int iw = flags[0];
    int r = rowIdx(ei, e, iw), c = colIdx(ei, e, iw);
    float nrm = F[DIS_O + r] * F[DIS_O + c];
    const float* xr = F + XF_O + (long)r * INC;
    float* ax = F + AGGX_O + (long)c * INC;
#pragma unroll
    for (int f = 0; f < INC; ++f) atomAddF(ax + f, nrm * xr[f]);
}

// K5: h = relu((agg_x + dis^2 * x) @ W1 + b1)
__global__ __launch_bounds__(256) void k_h(float* F) {
    int idx = blockIdx.x * 256 + threadIdx.x;
    if (idx >= NND * HID) return;
    int i = idx / HID, f = idx % HID;
    float s = F[DIS_O + i]; s *= s;
    const float* ax = F + AGGX_O + (long)i * INC;
    const float* xr = F + XF_O + (long)i * INC;
    float acc = F[B1F_O + f];
#pragma unroll
    for (int k = 0; k < INC; ++k)
        acc = fmaf(ax[k] + s * xr[k], F[W1F_O + k * HID + f], acc);
    F[H_O + idx] = fmaxf(acc, 0.0f);
}

// K6: agg_h[c] += norm * h[r]   (96 features; 4 per thread via float4 gather)
__global__ __launch_bounds__(256) void k_aggh(const int* ei, const int* flags, float* F) {
    int idx = blockIdx.x * 256 + threadIdx.x;
    if (idx >= NED * 24) return;
    int e = idx / 24, q = idx % 24;
    int iw = flags[0];
    int r = rowIdx(ei, e, iw), c = colIdx(ei, e, iw);
    float nrm = F[DIS_O + r] * F[DIS_O + c];
    const float4 hv = *(const float4*)(F + H_O + (long)r * HID + q * 4);
    float* ap = F + AGGH_O + (long)c * HID + q * 4;
    atomAddF(ap + 0, nrm * hv.x);
    atomAddF(ap + 1, nrm * hv.y);
    atomAddF(ap + 2, nrm * hv.z);
    atomAddF(ap + 3, nrm * hv.w);
}

// K7: v = agg_h + dis^2*h;  mu = v@W_mu + b_mu;  logstd = v@W_ls + b_ls
__global__ __launch_bounds__(256) void k_out(const float* F, const int* flags, void* dout) {
    int idx = blockIdx.x * 256 + threadIdx.x;
    if (idx >= NND * OUTC) return;
    int i = idx / OUTC, j = idx % OUTC;
    float s = F[DIS_O + i]; s *= s;
    const float* hg = F + AGGH_O + (long)i * HID;
    const float* hh = F + H_O + (long)i * HID;
    float am = F[BMF_O + j], al = F[BLF_O + j];
#pragma unroll 8
    for (int k = 0; k < HID; ++k) {
        float v = hg[k] + s * hh[k];
        am = fmaf(v, F[WMF_O + (long)k * OUTC + j], am);
        al = fmaf(v, F[WLF_O + (long)k * OUTC + j], al);
    }
    int ff = flags[1];
    if (ff) {
        float* o = (float*)dout;
        o[idx] = am; o[NOUT + idx] = al;
    } else {
        bf16* o = (bf16*)dout;
        o[idx] = __float2bfloat16(am);
        o[NOUT + idx] = __float2bfloat16(al);
    }
}

extern "C" void kernel_launch(void* const* d_in, const int* in_sizes, int n_in,
                              void* d_out, int out_size, void* d_ws, size_t ws_size,
                              hipStream_t stream) {
    const int* ei = (const int*)d_in[1];
    int* flags = (int*)d_ws;
    float* F = (float*)((char*)d_ws + 16);

    // zero deg + agg_x, and agg_h (h / converted inputs are fully overwritten)
    hipMemsetAsync((char*)d_ws + 16 + DIS_O * 4, 0, (AGGX_O + NND * 10L - DIS_O) * 4, stream);
    hipMemsetAsync((char*)d_ws + 16 + AGGH_O * 4, 0, (NND * 96L) * 4, stream);

    k_sniff<<<1, 256, 0, stream>>>(ei, (const unsigned short*)d_in[0], flags);
    k_convert<<<(CVT_TOT + 255) / 256, 256, 0, stream>>>(d_in[0], d_in[2], d_in[3], d_in[4],
                                                         d_in[5], d_in[6], d_in[7], flags, F);
    k_deg<<<(NED + 255) / 256, 256, 0, stream>>>(ei, flags, F);
    k_dis<<<(NND + 255) / 256, 256, 0, stream>>>(F);
    k_aggx<<<(NED + 255) / 256, 256, 0, stream>>>(ei, flags, F);
    k_h<<<(NND * HID + 255) / 256, 256, 0, stream>>>(F);
    k_aggh<<<(NED * 24 + 255) / 256, 256, 0, stream>>>(ei, flags, F);
    k_out<<<(NND * OUTC + 255) / 256, 256, 0, stream>>>(F, flags, d_out);
}

// Round 2
// 432.137 us; speedup vs baseline: 4.3326x; 4.3326x over previous
//
#include <hip/hip_runtime.h>
#include <hip/hip_bf16.h>

// Problem constants
#define NND 50000      // nodes
#define NED 800000     // edges (without self-loops)
#define INC 10
#define HID 96
#define OUTC 48
#define NOUT (NND*OUTC)   // 2,400,000 per output tensor

typedef __hip_bfloat16 bf16;

// ---- workspace float layout (after a 16-byte flag header) ----
#define XF_O   0L                 // 500000  (x: N x 10)
#define W1F_O  500000L            // 960
#define B1F_O  500960L            // 96
#define WMF_O  501056L            // 4608
#define BMF_O  505664L            // 48
#define WLF_O  505712L            // 4608
#define BLF_O  510320L            // 48
#define DIS_O  510368L            // N  (rsqrt(deg+1))
#define AGGX_O 560368L            // N*10 (includes self-loop term)
#define H_O    1060368L           // N*96
#define WS_FLOATS 5860368L        // ~23.4 MB
// ---- int region (offsets in ints from intBase) ----
#define CNT_IO   0L               // 50000
#define START_IO 50000L           // 50001 (+1 pad -> 50002)
#define CUR_IO   100002L          // 50000
#define EDGE_IO  150002L          // 800000 int2 (src, bitcast norm)

__device__ __forceinline__ float b2f(bf16 v) { return __bfloat162float(v); }

// edge-index accessors: iw=1 -> int64 storage (low word at 2*e), iw=0 -> int32
__device__ __forceinline__ int rowIdx(const int* ei, int e, int iw) {
    return iw ? ei[2 * e] : ei[e];
}
__device__ __forceinline__ int colIdx(const int* ei, int e, int iw) {
    return iw ? ei[2 * (NED + e)] : ei[NED + e];
}

// K0: runtime dtype sniffer (deterministic, same work every call)
__global__ __launch_bounds__(256) void k_sniff(const int* ei, const unsigned short* xs, int* flags) {
    __shared__ int s_oddnz, s_big;
    if (threadIdx.x == 0) { s_oddnz = 0; s_big = 0; }
    __syncthreads();
    int t = threadIdx.x;
    if (t < 128) {
        if (ei[2 * t + 1] != 0) atomicOr(&s_oddnz, 1);
    }
    for (int k = 0; k < 8; ++k) {
        unsigned short u = xs[t * 8 + k];
        float f = __uint_as_float(((unsigned int)u) << 16);
        if (!(fabsf(f) < 64.0f)) atomicOr(&s_big, 1);
    }
    __syncthreads();
    if (threadIdx.x == 0) {
        flags[0] = (s_oddnz == 0) ? 1 : 0;  // iw: 1 = int64
        flags[1] = s_big ? 1 : 0;           // ff: 1 = fp32
    }
}

// K1: convert all float inputs to fp32 in workspace
#define CVT_TOT 510368
__global__ __launch_bounds__(256) void k_convert(const void* x, const void* w1, const void* b1,
                                                 const void* wm, const void* bm,
                                                 const void* wl, const void* bl,
                                                 const int* flags, float* F) {
    int i = blockIdx.x * 256 + threadIdx.x;
    if (i >= CVT_TOT) return;
    int ff = flags[1];
    const void* src; long off;
    if      (i < 500000) { src = x;  off = i; }
    else if (i < 500960) { src = w1; off = i - 500000; }
    else if (i < 501056) { src = b1; off = i - 500960; }
    else if (i < 505664) { src = wm; off = i - 501056; }
    else if (i < 505712) { src = bm; off = i - 505664; }
    else if (i < 510320) { src = wl; off = i - 505712; }
    else                 { src = bl; off = i - 510320; }
    float v = ff ? ((const float*)src)[off] : b2f(((const bf16*)src)[off]);
    F[i] = v;
}

// K2: in-degree counts (int atomics)
__global__ __launch_bounds__(256) void k_deg(const int* ei, const int* flags, int* cnt) {
    int e = blockIdx.x * 256 + threadIdx.x;
    if (e >= NED) return;
    atomicAdd(&cnt[colIdx(ei, e, flags[0])], 1);
}

// K3: single-block exclusive scan over 50k counts -> start[], cursor[]
#define SC_CHUNK 49
__global__ __launch_bounds__(1024) void k_scan(const int* cnt, int* start, int* cursor) {
    __shared__ int lds[1024];
    int tid = threadIdx.x;
    int lo = tid * SC_CHUNK;
    int hi = lo + SC_CHUNK; if (hi > NND) hi = NND;
    int sum = 0;
    for (int i = lo; i < hi; ++i) sum += cnt[i];
    lds[tid] = sum;
    __syncthreads();
    int incl = sum;
    for (int off = 1; off < 1024; off <<= 1) {
        int t = (tid >= off) ? lds[tid - off] : 0;
        __syncthreads();
        incl += t; lds[tid] = incl;
        __syncthreads();
    }
    int run = incl - sum;
    for (int i = lo; i < hi; ++i) { start[i] = run; cursor[i] = run; run += cnt[i]; }
    if (tid == 1023) start[NND] = incl;
}

// K4: dis = rsqrt(deg+1)
__global__ __launch_bounds__(256) void k_dis(const int* cnt, float* F) {
    int i = blockIdx.x * 256 + threadIdx.x;
    if (i >= NND) return;
    F[DIS_O + i] = rsqrtf((float)cnt[i] + 1.0f);
}

// K5: scatter edges into CSR order (record = {src, norm})
__global__ __launch_bounds__(256) void k_scatter(const int* ei, const int* flags,
                                                 const float* F, int* cursor, int2* edges) {
    int e = blockIdx.x * 256 + threadIdx.x;
    if (e >= NED) return;
    int iw = flags[0];
    int r = rowIdx(ei, e, iw), c = colIdx(ei, e, iw);
    int pos = atomicAdd(&cursor[c], 1);
    float nrm = F[DIS_O + r] * F[DIS_O + c];
    edges[pos] = make_int2(r, __float_as_int(nrm));
}

// K6: gather-aggregate x (10 features) + self-loop term
__global__ __launch_bounds__(256) void k_gaggx(const int* start, const int2* edges, float* F) {
    int idx = blockIdx.x * 256 + threadIdx.x;
    if (idx >= NND * INC) return;
    int node = idx / INC, f = idx % INC;
    int s = start[node], t = start[node + 1];
    float acc = 0.0f;
    for (int k = s; k < t; ++k) {
        int2 rec = edges[k];
        acc = fmaf(__int_as_float(rec.y), F[XF_O + (long)rec.x * INC + f], acc);
    }
    float d = F[DIS_O + node];
    acc = fmaf(d * d, F[XF_O + (long)node * INC + f], acc);
    F[AGGX_O + idx] = acc;
}

// K7: h = relu(agg_x @ W1 + b1)
__global__ __launch_bounds__(256) void k_h(float* F) {
    int idx = blockIdx.x * 256 + threadIdx.x;
    if (idx >= NND * HID) return;
    int i = idx / HID, f = idx % HID;
    const float* ax = F + AGGX_O + (long)i * INC;
    float acc = F[B1F_O + f];
#pragma unroll
    for (int k = 0; k < INC; ++k)
        acc = fmaf(ax[k], F[W1F_O + k * HID + f], acc);
    F[H_O + idx] = fmaxf(acc, 0.0f);
}

// K8: one wave per node — gather-aggregate h (96 feats) in registers, add
// self-loop, LDS round-trip, fused dual GEMV epilogue (mu, logstd) + store.
// grid = 12500 blocks x 256 threads = exactly 50000 waves, no early returns.
__global__ __launch_bounds__(256) void k_gaggh_out(const int* start, const int2* edges,
                                                   const float* F, const int* flags, void* dout) {
    __shared__ float vbuf[4][HID];
    int wid = threadIdx.x >> 6;
    int lane = threadIdx.x & 63;
    int node = blockIdx.x * 4 + wid;

    int s = start[node], t = start[node + 1];
    float a0 = 0.0f, a1 = 0.0f;   // feature lane, feature 64+lane (lane<32)
    int k = s;
    for (; k + 1 < t; k += 2) {
        int2 r0 = edges[k], r1 = edges[k + 1];
        float n0 = __int_as_float(r0.y), n1 = __int_as_float(r1.y);
        const float* h0 = F + H_O + (long)r0.x * HID;
        const float* h1 = F + H_O + (long)r1.x * HID;
        a0 = fmaf(n0, h0[lane], a0);
        a0 = fmaf(n1, h1[lane], a0);
        if (lane < 32) {
            a1 = fmaf(n0, h0[64 + lane], a1);
            a1 = fmaf(n1, h1[64 + lane], a1);
        }
    }
    if (k < t) {
        int2 r0 = edges[k];
        float n0 = __int_as_float(r0.y);
        const float* h0 = F + H_O + (long)r0.x * HID;
        a0 = fmaf(n0, h0[lane], a0);
        if (lane < 32) a1 = fmaf(n0, h0[64 + lane], a1);
    }
    // self-loop
    float d = F[DIS_O + node]; float dd = d * d;
    const float* hn = F + H_O + (long)node * HID;
    a0 = fmaf(dd, hn[lane], a0);
    if (lane < 32) a1 = fmaf(dd, hn[64 + lane], a1);

    vbuf[wid][lane] = a0;
    if (lane < 32) vbuf[wid][64 + lane] = a1;
    __syncthreads();

    if (lane < OUTC) {
        float am = F[BMF_O + lane], al = F[BLF_O + lane];
#pragma unroll 8
        for (int kk = 0; kk < HID; ++kk) {
            float v = vbuf[wid][kk];
            am = fmaf(v, F[WMF_O + (long)kk * OUTC + lane], am);
            al = fmaf(v, F[WLF_O + (long)kk * OUTC + lane], al);
        }
        long oi = (long)node * OUTC + lane;
        if (flags[1]) {
            float* o = (float*)dout;
            o[oi] = am; o[NOUT + oi] = al;
        } else {
            bf16* o = (bf16*)dout;
            o[oi] = __float2bfloat16(am);
            o[NOUT + oi] = __float2bfloat16(al);
        }
    }
}

extern "C" void kernel_launch(void* const* d_in, const int* in_sizes, int n_in,
                              void* d_out, int out_size, void* d_ws, size_t ws_size,
                              hipStream_t stream) {
    const int* ei = (const int*)d_in[1];
    int* flags = (int*)d_ws;
    float* F = (float*)((char*)d_ws + 16);
    int* intBase = (int*)((char*)d_ws + 16 + WS_FLOATS * 4);
    int* cnt    = intBase + CNT_IO;
    int* start  = intBase + START_IO;
    int* cursor = intBase + CUR_IO;
    int2* edges = (int2*)(intBase + EDGE_IO);

    hipMemsetAsync(cnt, 0, NND * 4, stream);

    k_sniff<<<1, 256, 0, stream>>>(ei, (const unsigned short*)d_in[0], flags);
    k_convert<<<(CVT_TOT + 255) / 256, 256, 0, stream>>>(d_in[0], d_in[2], d_in[3], d_in[4],
                                                         d_in[5], d_in[6], d_in[7], flags, F);
    k_deg<<<(NED + 255) / 256, 256, 0, stream>>>(ei, flags, cnt);
    k_scan<<<1, 1024, 0, stream>>>(cnt, start, cursor);
    k_dis<<<(NND + 255) / 256, 256, 0, stream>>>(cnt, F);
    k_scatter<<<(NED + 255) / 256, 256, 0, stream>>>(ei, flags, F, cursor, edges);
    k_gaggx<<<(NND * INC + 255) / 256, 256, 0, stream>>>(start, edges, F);
    k_h<<<(NND * HID + 255) / 256, 256, 0, stream>>>(F);
    k_gaggh_out<<<NND / 4, 256, 0, stream>>>(start, edges, F, flags, d_out);
}

// Round 3
// 419.067 us; speedup vs baseline: 4.4677x; 1.0312x over previous
//
#include <hip/hip_runtime.h>
#include <hip/hip_bf16.h>

// Problem constants
#define NND 50000      // nodes
#define NED 800000     // edges (without self-loops)
#define INC 10
#define HID 96
#define OUTC 48
#define NOUT (NND*OUTC)

typedef __hip_bfloat16 bf16;

// ---- workspace layout ----
// [0,16): flags.  Float region (offsets in floats from F):
#define XF_O   0L                 // 500000  (x: N x 10)
#define W1F_O  500000L            // 960   (W1 then b1 contiguous: 1056)
#define B1F_O  500960L            // 96
#define WMF_O  501056L            // 4608
#define BMF_O  505664L            // 48
#define WLF_O  505712L            // 4608
#define BLF_O  510320L            // 48
#define DIS_O  510368L            // 50000 (rsqrt(deg+1))
#define FLOATS_TOT 560368L
// bf16 h region: NND*96 ushorts right after floats.
// int region after h: cnt / start / cursor / edges(int2)
#define CNT_IO   0L               // 50000
#define START_IO 50000L           // 50001 (+1 pad)
#define CUR_IO   100002L          // 50000
#define EDGE_IO  150002L          // 800000 int2 {src, bitcast norm}

__device__ __forceinline__ float b2f(bf16 v) { return __bfloat162float(v); }
__device__ __forceinline__ float bfLo(unsigned int p) { return __uint_as_float(p << 16); }
__device__ __forceinline__ float bfHi(unsigned int p) { return __uint_as_float(p & 0xffff0000u); }

// edge-index accessors: iw=1 -> int64 storage, iw=0 -> int32
__device__ __forceinline__ int rowIdx(const int* ei, int e, int iw) {
    return iw ? ei[2 * e] : ei[e];
}
__device__ __forceinline__ int colIdx(const int* ei, int e, int iw) {
    return iw ? ei[2 * (NED + e)] : ei[NED + e];
}

// K0: runtime dtype sniffer (deterministic every call)
__global__ __launch_bounds__(256) void k_sniff(const int* ei, const unsigned short* xs, int* flags) {
    __shared__ int s_oddnz, s_big;
    if (threadIdx.x == 0) { s_oddnz = 0; s_big = 0; }
    __syncthreads();
    int t = threadIdx.x;
    if (t < 128) {
        if (ei[2 * t + 1] != 0) atomicOr(&s_oddnz, 1);
    }
    for (int k = 0; k < 8; ++k) {
        unsigned short u = xs[t * 8 + k];
        float f = __uint_as_float(((unsigned int)u) << 16);
        if (!(fabsf(f) < 64.0f)) atomicOr(&s_big, 1);
    }
    __syncthreads();
    if (threadIdx.x == 0) {
        flags[0] = (s_oddnz == 0) ? 1 : 0;  // iw: 1 = int64
        flags[1] = s_big ? 1 : 0;           // ff: 1 = fp32
    }
}

// K1: fused convert-to-fp32 + degree count (deg: 4 edges/thread via int4)
#define CVT_TOT 510368
#define DEG_THREADS 200000
__global__ __launch_bounds__(256) void k_prep(const void* x, const void* w1, const void* b1,
                                              const void* wm, const void* bm,
                                              const void* wl, const void* bl,
                                              const int* ei, const int* flags,
                                              float* F, int* cnt) {
    int idx = blockIdx.x * 256 + threadIdx.x;
    if (idx < CVT_TOT) {
        int ff = flags[1];
        const void* src; long off;
        if      (idx < 500000) { src = x;  off = idx; }
        else if (idx < 500960) { src = w1; off = idx - 500000; }
        else if (idx < 501056) { src = b1; off = idx - 500960; }
        else if (idx < 505664) { src = wm; off = idx - 501056; }
        else if (idx < 505712) { src = bm; off = idx - 505664; }
        else if (idx < 510320) { src = wl; off = idx - 505712; }
        else                   { src = bl; off = idx - 510320; }
        F[idx] = ff ? ((const float*)src)[off] : b2f(((const bf16*)src)[off]);
    } else if (idx < CVT_TOT + DEG_THREADS) {
        int j = idx - CVT_TOT;
        if (flags[0]) {
            const int4* p = (const int4*)(ei + 2L * NED);
            int4 a = p[2 * j], b = p[2 * j + 1];
            atomicAdd(&cnt[a.x], 1); atomicAdd(&cnt[a.z], 1);
            atomicAdd(&cnt[b.x], 1); atomicAdd(&cnt[b.z], 1);
        } else {
            const int4* p = (const int4*)(ei + NED);
            int4 a = p[j];
            atomicAdd(&cnt[a.x], 1); atomicAdd(&cnt[a.y], 1);
            atomicAdd(&cnt[a.z], 1); atomicAdd(&cnt[a.w], 1);
        }
    }
}

// K2: single-block exclusive scan -> start[], cursor[]; also dis=rsqrt(deg+1)
#define SC_CHUNK 49
__global__ __launch_bounds__(1024) void k_scan(const int* cnt, int* start, int* cursor, float* F) {
    __shared__ int lds[1024];
    int tid = threadIdx.x;
    int lo = tid * SC_CHUNK;
    int hi = lo + SC_CHUNK; if (hi > NND) hi = NND;
    int sum = 0;
    for (int i = lo; i < hi; ++i) sum += cnt[i];
    lds[tid] = sum;
    __syncthreads();
    int incl = sum;
    for (int off = 1; off < 1024; off <<= 1) {
        int t = (tid >= off) ? lds[tid - off] : 0;
        __syncthreads();
        incl += t; lds[tid] = incl;
        __syncthreads();
    }
    int run = incl - sum;
    for (int i = lo; i < hi; ++i) {
        int c = cnt[i];
        start[i] = run; cursor[i] = run; run += c;
        F[DIS_O + i] = rsqrtf((float)c + 1.0f);
    }
    if (tid == 1023) start[NND] = incl;
}

// K3: scatter edges into CSR order, 2 edges/thread (record = {src, norm})
__global__ __launch_bounds__(256) void k_scatter(const int* ei, const int* flags,
                                                 const float* F, int* cursor, int2* edges) {
    int j = blockIdx.x * 256 + threadIdx.x;
    if (j >= NED / 2) return;
    int iw = flags[0];
    int r0, c0, r1, c1;
    if (iw) {
        int4 rr = ((const int4*)ei)[j];
        int4 cc = ((const int4*)(ei + 2L * NED))[j];
        r0 = rr.x; r1 = rr.z; c0 = cc.x; c1 = cc.z;
    } else {
        int2 rr = ((const int2*)ei)[j];
        int2 cc = ((const int2*)(ei + NED))[j];
        r0 = rr.x; r1 = rr.y; c0 = cc.x; c1 = cc.y;
    }
    int p0 = atomicAdd(&cursor[c0], 1);
    edges[p0] = make_int2(r0, __float_as_int(F[DIS_O + r0] * F[DIS_O + c0]));
    int p1 = atomicAdd(&cursor[c1], 1);
    edges[p1] = make_int2(r1, __float_as_int(F[DIS_O + r1] * F[DIS_O + c1]));
}

// K4: fused layer1 — thread per node: gather-agg x (10 feats, regs) then
// h = relu(agg @ W1 + b1) from LDS weights, stored as packed bf16.
__global__ __launch_bounds__(256) void k_layer1(const int* start, const int2* edges,
                                                const float* F, unsigned short* h) {
    __shared__ float w1s[1056];   // W1 (960) then b1 (96), contiguous in F
    for (int i = threadIdx.x; i < 1056; i += 256) w1s[i] = F[W1F_O + i];
    __syncthreads();
    int node = blockIdx.x * 256 + threadIdx.x;
    if (node >= NND) return;
    float ax[INC];
#pragma unroll
    for (int j = 0; j < INC; ++j) ax[j] = 0.0f;
    int s = start[node], t = start[node + 1];
    for (int k = s; k < t; ++k) {
        int2 rec = edges[k];
        float n = __int_as_float(rec.y);
        const float2* xr = (const float2*)(F + XF_O + (long)rec.x * INC);
#pragma unroll
        for (int j = 0; j < 5; ++j) {
            float2 v = xr[j];
            ax[2 * j]     = fmaf(n, v.x, ax[2 * j]);
            ax[2 * j + 1] = fmaf(n, v.y, ax[2 * j + 1]);
        }
    }
    float d = F[DIS_O + node]; float dd = d * d;
    {
        const float2* xr = (const float2*)(F + XF_O + (long)node * INC);
#pragma unroll
        for (int j = 0; j < 5; ++j) {
            float2 v = xr[j];
            ax[2 * j]     = fmaf(dd, v.x, ax[2 * j]);
            ax[2 * j + 1] = fmaf(dd, v.y, ax[2 * j + 1]);
        }
    }
    unsigned int* hrow = (unsigned int*)(h + (size_t)node * HID);
#pragma unroll 4
    for (int f = 0; f < HID; f += 2) {
        float a0 = w1s[960 + f], a1 = w1s[960 + f + 1];
#pragma unroll
        for (int kk = 0; kk < INC; ++kk) {
            a0 = fmaf(ax[kk], w1s[kk * HID + f], a0);
            a1 = fmaf(ax[kk], w1s[kk * HID + f + 1], a1);
        }
        a0 = fmaxf(a0, 0.0f); a1 = fmaxf(a1, 0.0f);
        unsigned int u0 = __bfloat16_as_ushort(__float2bfloat16(a0));
        unsigned int u1 = __bfloat16_as_ushort(__float2bfloat16(a1));
        hrow[f >> 1] = u0 | (u1 << 16);
    }
}

// K5: one wave per node — gather-agg bf16 h (lane<48 holds feats 2L,2L+1),
// self-loop, LDS round-trip, fused dual GEMV (mu, logstd) + store.
__global__ __launch_bounds__(256) void k_gaggh_out(const int* start, const int2* edges,
                                                   const float* F, const unsigned short* h,
                                                   const int* flags, void* dout) {
    __shared__ float vbuf[4][HID];
    int wid = threadIdx.x >> 6;
    int lane = threadIdx.x & 63;
    int node = blockIdx.x * 4 + wid;
    const unsigned int* hb = (const unsigned int*)h;

    if (lane < 48) {
        int s = start[node], t = start[node + 1];
        float a0 = 0.0f, a1 = 0.0f;
        int k = s;
        for (; k + 3 < t; k += 4) {
            int2 r0 = edges[k], r1 = edges[k + 1], r2 = edges[k + 2], r3 = edges[k + 3];
            unsigned int p0 = hb[(size_t)r0.x * 48 + lane];
            unsigned int p1 = hb[(size_t)r1.x * 48 + lane];
            unsigned int p2 = hb[(size_t)r2.x * 48 + lane];
            unsigned int p3 = hb[(size_t)r3.x * 48 + lane];
            float n0 = __int_as_float(r0.y), n1 = __int_as_float(r1.y);
            float n2 = __int_as_float(r2.y), n3 = __int_as_float(r3.y);
            a0 = fmaf(n0, bfLo(p0), a0); a1 = fmaf(n0, bfHi(p0), a1);
            a0 = fmaf(n1, bfLo(p1), a0); a1 = fmaf(n1, bfHi(p1), a1);
            a0 = fmaf(n2, bfLo(p2), a0); a1 = fmaf(n2, bfHi(p2), a1);
            a0 = fmaf(n3, bfLo(p3), a0); a1 = fmaf(n3, bfHi(p3), a1);
        }
        for (; k < t; ++k) {
            int2 r0 = edges[k];
            unsigned int p0 = hb[(size_t)r0.x * 48 + lane];
            float n0 = __int_as_float(r0.y);
            a0 = fmaf(n0, bfLo(p0), a0); a1 = fmaf(n0, bfHi(p0), a1);
        }
        float d = F[DIS_O + node]; float dd = d * d;
        unsigned int ps = hb[(size_t)node * 48 + lane];
        a0 = fmaf(dd, bfLo(ps), a0); a1 = fmaf(dd, bfHi(ps), a1);
        ((float2*)vbuf[wid])[lane] = make_float2(a0, a1);
    }
    __syncthreads();

    if (lane < OUTC) {
        float am = F[BMF_O + lane], al = F[BLF_O + lane];
#pragma unroll 8
        for (int kk = 0; kk < HID; ++kk) {
            float v = vbuf[wid][kk];
            am = fmaf(v, F[WMF_O + (long)kk * OUTC + lane], am);
            al = fmaf(v, F[WLF_O + (long)kk * OUTC + lane], al);
        }
        long oi = (long)node * OUTC + lane;
        if (flags[1]) {
            float* o = (float*)dout;
            o[oi] = am; o[NOUT + oi] = al;
        } else {
            bf16* o = (bf16*)dout;
            o[oi] = __float2bfloat16(am);
            o[NOUT + oi] = __float2bfloat16(al);
        }
    }
}

extern "C" void kernel_launch(void* const* d_in, const int* in_sizes, int n_in,
                              void* d_out, int out_size, void* d_ws, size_t ws_size,
                              hipStream_t stream) {
    const int* ei = (const int*)d_in[1];
    int* flags = (int*)d_ws;
    float* F = (float*)((char*)d_ws + 16);
    unsigned short* h = (unsigned short*)((char*)d_ws + 16 + FLOATS_TOT * 4);
    int* intBase = (int*)((char*)h + (size_t)NND * HID * 2);
    int* cnt    = intBase + CNT_IO;
    int* start  = intBase + START_IO;
    int* cursor = intBase + CUR_IO;
    int2* edges = (int2*)(intBase + EDGE_IO);

    hipMemsetAsync(cnt, 0, NND * 4, stream);

    k_sniff<<<1, 256, 0, stream>>>(ei, (const unsigned short*)d_in[0], flags);
    k_prep<<<(CVT_TOT + DEG_THREADS + 255) / 256, 256, 0, stream>>>(
        d_in[0], d_in[2], d_in[3], d_in[4], d_in[5], d_in[6], d_in[7], ei, flags, F, cnt);
    k_scan<<<1, 1024, 0, stream>>>(cnt, start, cursor, F);
    k_scatter<<<(NED / 2 + 255) / 256, 256, 0, stream>>>(ei, flags, F, cursor, edges);
    k_layer1<<<(NND + 255) / 256, 256, 0, stream>>>(start, edges, F, h);
    k_gaggh_out<<<NND / 4, 256, 0, stream>>>(start, edges, F, h, flags, d_out);
}

// Round 4
// 295.309 us; speedup vs baseline: 6.3401x; 1.4191x over previous
//
#include <hip/hip_runtime.h>
#include <hip/hip_bf16.h>

// Problem constants
#define NND 50000      // nodes
#define NED 800000     // edges (without self-loops)
#define INC 10
#define HID 96
#define OUTC 48
#define NOUT (NND*OUTC)
#define NBLK 196       // ceil(NND/256)

typedef __hip_bfloat16 bf16;

// ---- workspace layout ----
// [0,16): flags.  Float region (offsets in floats from F):
#define XF_O   0L                 // 500000  (x: N x 10)
#define W1F_O  500000L            // 960   (W1 then b1 contiguous: 1056)
#define B1F_O  500960L            // 96
#define WMF_O  501056L            // 4608
#define BMF_O  505664L            // 48
#define WLF_O  505712L            // 4608
#define BLF_O  510320L            // 48
#define DIS_O  510368L            // 50000 (rsqrt(deg+1))
#define FLOATS_TOT 560368L
// bf16 h region: NND*96 ushorts right after floats.
// int region after h: cnt / start / cursor / bsum / boff / edges(int2)
#define CNT_IO   0L               // 50000
#define START_IO 50000L           // 50001 (+1 pad)
#define CUR_IO   100002L          // 50000
#define BS_IO    150002L          // 256
#define BOFF_IO  150258L          // 256 (pad to even)
#define EDGE_IO  150528L          // 800000 int2 {src, bitcast norm}; 8B-aligned

__device__ __forceinline__ float b2f(bf16 v) { return __bfloat162float(v); }
__device__ __forceinline__ float bfLo(unsigned int p) { return __uint_as_float(p << 16); }
__device__ __forceinline__ float bfHi(unsigned int p) { return __uint_as_float(p & 0xffff0000u); }

// K0: runtime dtype sniffer (deterministic every call)
__global__ __launch_bounds__(256) void k_sniff(const int* ei, const unsigned short* xs, int* flags) {
    __shared__ int s_oddnz, s_big;
    if (threadIdx.x == 0) { s_oddnz = 0; s_big = 0; }
    __syncthreads();
    int t = threadIdx.x;
    if (t < 128) {
        if (ei[2 * t + 1] != 0) atomicOr(&s_oddnz, 1);
    }
    for (int k = 0; k < 8; ++k) {
        unsigned short u = xs[t * 8 + k];
        float f = __uint_as_float(((unsigned int)u) << 16);
        if (!(fabsf(f) < 64.0f)) atomicOr(&s_big, 1);
    }
    __syncthreads();
    if (threadIdx.x == 0) {
        flags[0] = (s_oddnz == 0) ? 1 : 0;  // iw: 1 = int64
        flags[1] = s_big ? 1 : 0;           // ff: 1 = fp32
    }
}

// K1: fused convert-to-fp32 + degree count (deg: 4 edges/thread via int4)
#define CVT_TOT 510368
#define DEG_THREADS 200000
__global__ __launch_bounds__(256) void k_prep(const void* x, const void* w1, const void* b1,
                                              const void* wm, const void* bm,
                                              const void* wl, const void* bl,
                                              const int* ei, const int* flags,
                                              float* F, int* cnt) {
    int idx = blockIdx.x * 256 + threadIdx.x;
    if (idx < CVT_TOT) {
        int ff = flags[1];
        const void* src; long off;
        if      (idx < 500000) { src = x;  off = idx; }
        else if (idx < 500960) { src = w1; off = idx - 500000; }
        else if (idx < 501056) { src = b1; off = idx - 500960; }
        else if (idx < 505664) { src = wm; off = idx - 501056; }
        else if (idx < 505712) { src = bm; off = idx - 505664; }
        else if (idx < 510320) { src = wl; off = idx - 505712; }
        else                   { src = bl; off = idx - 510320; }
        F[idx] = ff ? ((const float*)src)[off] : b2f(((const bf16*)src)[off]);
    } else if (idx < CVT_TOT + DEG_THREADS) {
        int j = idx - CVT_TOT;
        if (flags[0]) {
            const int4* p = (const int4*)(ei + 2L * NED);
            int4 a = p[2 * j], b = p[2 * j + 1];
            atomicAdd(&cnt[a.x], 1); atomicAdd(&cnt[a.z], 1);
            atomicAdd(&cnt[b.x], 1); atomicAdd(&cnt[b.z], 1);
        } else {
            const int4* p = (const int4*)(ei + NED);
            int4 a = p[j];
            atomicAdd(&cnt[a.x], 1); atomicAdd(&cnt[a.y], 1);
            atomicAdd(&cnt[a.z], 1); atomicAdd(&cnt[a.w], 1);
        }
    }
}

// K2a: per-block sums of cnt (wave shuffle reduce)
__global__ __launch_bounds__(256) void k_bsum(const int* cnt, int* bsum) {
    int i = blockIdx.x * 256 + threadIdx.x;
    int v = (i < NND) ? cnt[i] : 0;
#pragma unroll
    for (int off = 32; off >= 1; off >>= 1) v += __shfl_down(v, off, 64);
    __shared__ int ws[4];
    int wid = threadIdx.x >> 6, lane = threadIdx.x & 63;
    if (lane == 0) ws[wid] = v;
    __syncthreads();
    if (threadIdx.x == 0) bsum[blockIdx.x] = ws[0] + ws[1] + ws[2] + ws[3];
}

// K2b: single small block scans the 196 block sums -> exclusive offsets
__global__ __launch_bounds__(256) void k_scan2(const int* bsum, int* boff) {
    __shared__ int lds[256];
    int tid = threadIdx.x;
    int v = (tid < NBLK) ? bsum[tid] : 0;
    lds[tid] = v;
    __syncthreads();
    int incl = v;
    for (int off = 1; off < 256; off <<= 1) {
        int t = (tid >= off) ? lds[tid - off] : 0;
        __syncthreads();
        incl += t; lds[tid] = incl;
        __syncthreads();
    }
    if (tid < NBLK) boff[tid] = incl - v;
}

// K2c: block-local exclusive scan + offset -> start/cursor; dis=rsqrt(deg+1)
__global__ __launch_bounds__(256) void k_fill(const int* cnt, const int* boff,
                                              int* start, int* cursor, float* F) {
    __shared__ int lds[256];
    int tid = threadIdx.x;
    int i = blockIdx.x * 256 + tid;
    int c = (i < NND) ? cnt[i] : 0;
    lds[tid] = c;
    __syncthreads();
    int incl = c;
    for (int off = 1; off < 256; off <<= 1) {
        int t = (tid >= off) ? lds[tid - off] : 0;
        __syncthreads();
        incl += t; lds[tid] = incl;
        __syncthreads();
    }
    int run = boff[blockIdx.x] + incl - c;
    if (i <= NND) start[i] = run;        // i==NND lands here -> total == NED
    if (i < NND) {
        cursor[i] = run;
        F[DIS_O + i] = rsqrtf((float)c + 1.0f);
    }
}

// K3: scatter edges into CSR order, 2 edges/thread (record = {src, norm})
__global__ __launch_bounds__(256) void k_scatter(const int* ei, const int* flags,
                                                 const float* F, int* cursor, int2* edges) {
    int j = blockIdx.x * 256 + threadIdx.x;
    if (j >= NED / 2) return;
    int iw = flags[0];
    int r0, c0, r1, c1;
    if (iw) {
        int4 rr = ((const int4*)ei)[j];
        int4 cc = ((const int4*)(ei + 2L * NED))[j];
        r0 = rr.x; r1 = rr.z; c0 = cc.x; c1 = cc.z;
    } else {
        int2 rr = ((const int2*)ei)[j];
        int2 cc = ((const int2*)(ei + NED))[j];
        r0 = rr.x; r1 = rr.y; c0 = cc.x; c1 = cc.y;
    }
    int p0 = atomicAdd(&cursor[c0], 1);
    edges[p0] = make_int2(r0, __float_as_int(F[DIS_O + r0] * F[DIS_O + c0]));
    int p1 = atomicAdd(&cursor[c1], 1);
    edges[p1] = make_int2(r1, __float_as_int(F[DIS_O + r1] * F[DIS_O + c1]));
}

// K4: fused layer1 — thread per node: gather-agg x (10 feats, regs) then
// h = relu(agg @ W1 + b1) from LDS weights, stored as packed bf16.
__global__ __launch_bounds__(256) void k_layer1(const int* start, const int2* edges,
                                                const float* F, unsigned short* h) {
    __shared__ float w1s[1056];   // W1 (960) then b1 (96), contiguous in F
    for (int i = threadIdx.x; i < 1056; i += 256) w1s[i] = F[W1F_O + i];
    __syncthreads();
    int node = blockIdx.x * 256 + threadIdx.x;
    if (node >= NND) return;
    float ax[INC];
#pragma unroll
    for (int j = 0; j < INC; ++j) ax[j] = 0.0f;
    int s = start[node], t = start[node + 1];
    for (int k = s; k < t; ++k) {
        int2 rec = edges[k];
        float n = __int_as_float(rec.y);
        const float2* xr = (const float2*)(F + XF_O + (long)rec.x * INC);
#pragma unroll
        for (int j = 0; j < 5; ++j) {
            float2 v = xr[j];
            ax[2 * j]     = fmaf(n, v.x, ax[2 * j]);
            ax[2 * j + 1] = fmaf(n, v.y, ax[2 * j + 1]);
        }
    }
    float d = F[DIS_O + node]; float dd = d * d;
    {
        const float2* xr = (const float2*)(F + XF_O + (long)node * INC);
#pragma unroll
        for (int j = 0; j < 5; ++j) {
            float2 v = xr[j];
            ax[2 * j]     = fmaf(dd, v.x, ax[2 * j]);
            ax[2 * j + 1] = fmaf(dd, v.y, ax[2 * j + 1]);
        }
    }
    unsigned int* hrow = (unsigned int*)(h + (size_t)node * HID);
#pragma unroll 4
    for (int f = 0; f < HID; f += 2) {
        float a0 = w1s[960 + f], a1 = w1s[960 + f + 1];
#pragma unroll
        for (int kk = 0; kk < INC; ++kk) {
            a0 = fmaf(ax[kk], w1s[kk * HID + f], a0);
            a1 = fmaf(ax[kk], w1s[kk * HID + f + 1], a1);
        }
        a0 = fmaxf(a0, 0.0f); a1 = fmaxf(a1, 0.0f);
        unsigned int u0 = __bfloat16_as_ushort(__float2bfloat16(a0));
        unsigned int u1 = __bfloat16_as_ushort(__float2bfloat16(a1));
        hrow[f >> 1] = u0 | (u1 << 16);
    }
}

// K5: one wave per node — gather-agg bf16 h (lane<48 holds feats 2L,2L+1),
// self-loop, LDS round-trip, fused dual GEMV (mu, logstd) + store.
__global__ __launch_bounds__(256) void k_gaggh_out(const int* start, const int2* edges,
                                                   const float* F, const unsigned short* h,
                                                   const int* flags, void* dout) {
    __shared__ float vbuf[4][HID];
    int wid = threadIdx.x >> 6;
    int lane = threadIdx.x & 63;
    int node = blockIdx.x * 4 + wid;
    const unsigned int* hb = (const unsigned int*)h;

    if (lane < 48) {
        int s = start[node], t = start[node + 1];
        float a0 = 0.0f, a1 = 0.0f;
        int k = s;
        for (; k + 3 < t; k += 4) {
            int2 r0 = edges[k], r1 = edges[k + 1], r2 = edges[k + 2], r3 = edges[k + 3];
            unsigned int p0 = hb[(size_t)r0.x * 48 + lane];
            unsigned int p1 = hb[(size_t)r1.x * 48 + lane];
            unsigned int p2 = hb[(size_t)r2.x * 48 + lane];
            unsigned int p3 = hb[(size_t)r3.x * 48 + lane];
            float n0 = __int_as_float(r0.y), n1 = __int_as_float(r1.y);
            float n2 = __int_as_float(r2.y), n3 = __int_as_float(r3.y);
            a0 = fmaf(n0, bfLo(p0), a0); a1 = fmaf(n0, bfHi(p0), a1);
            a0 = fmaf(n1, bfLo(p1), a0); a1 = fmaf(n1, bfHi(p1), a1);
            a0 = fmaf(n2, bfLo(p2), a0); a1 = fmaf(n2, bfHi(p2), a1);
            a0 = fmaf(n3, bfLo(p3), a0); a1 = fmaf(n3, bfHi(p3), a1);
        }
        for (; k < t; ++k) {
            int2 r0 = edges[k];
            unsigned int p0 = hb[(size_t)r0.x * 48 + lane];
            float n0 = __int_as_float(r0.y);
            a0 = fmaf(n0, bfLo(p0), a0); a1 = fmaf(n0, bfHi(p0), a1);
        }
        float d = F[DIS_O + node]; float dd = d * d;
        unsigned int ps = hb[(size_t)node * 48 + lane];
        a0 = fmaf(dd, bfLo(ps), a0); a1 = fmaf(dd, bfHi(ps), a1);
        ((float2*)vbuf[wid])[lane] = make_float2(a0, a1);
    }
    __syncthreads();

    if (lane < OUTC) {
        float am = F[BMF_O + lane], al = F[BLF_O + lane];
#pragma unroll 8
        for (int kk = 0; kk < HID; ++kk) {
            float v = vbuf[wid][kk];
            am = fmaf(v, F[WMF_O + (long)kk * OUTC + lane], am);
            al = fmaf(v, F[WLF_O + (long)kk * OUTC + lane], al);
        }
        long oi = (long)node * OUTC + lane;
        if (flags[1]) {
            float* o = (float*)dout;
            o[oi] = am; o[NOUT + oi] = al;
        } else {
            bf16* o = (bf16*)dout;
            o[oi] = __float2bfloat16(am);
            o[NOUT + oi] = __float2bfloat16(al);
        }
    }
}

extern "C" void kernel_launch(void* const* d_in, const int* in_sizes, int n_in,
                              void* d_out, int out_size, void* d_ws, size_t ws_size,
                              hipStream_t stream) {
    const int* ei = (const int*)d_in[1];
    int* flags = (int*)d_ws;
    float* F = (float*)((char*)d_ws + 16);
    unsigned short* h = (unsigned short*)((char*)d_ws + 16 + FLOATS_TOT * 4);
    int* intBase = (int*)((char*)h + (size_t)NND * HID * 2);
    int* cnt    = intBase + CNT_IO;
    int* start  = intBase + START_IO;
    int* cursor = intBase + CUR_IO;
    int* bsum   = intBase + BS_IO;
    int* boff   = intBase + BOFF_IO;
    int2* edges = (int2*)(intBase + EDGE_IO);

    hipMemsetAsync(cnt, 0, NND * 4, stream);

    k_sniff<<<1, 256, 0, stream>>>(ei, (const unsigned short*)d_in[0], flags);
    k_prep<<<(CVT_TOT + DEG_THREADS + 255) / 256, 256, 0, stream>>>(
        d_in[0], d_in[2], d_in[3], d_in[4], d_in[5], d_in[6], d_in[7], ei, flags, F, cnt);
    k_bsum<<<NBLK, 256, 0, stream>>>(cnt, bsum);
    k_scan2<<<1, 256, 0, stream>>>(bsum, boff);
    k_fill<<<NBLK, 256, 0, stream>>>(cnt, boff, start, cursor, F);
    k_scatter<<<(NED / 2 + 255) / 256, 256, 0, stream>>>(ei, flags, F, cursor, edges);
    k_layer1<<<(NND + 255) / 256, 256, 0, stream>>>(start, edges, F, h);
    k_gaggh_out<<<NND / 4, 256, 0, stream>>>(start, edges, F, h, flags, d_out);
}